// Round 3
// baseline (94.379 us; speedup 1.0000x reference)
//
#include <hip/hip_runtime.h>

#define BN 512   // batch
#define DD 512   // feature dim
#define LL 24    // label dim

// ws layout (float words):
//   [0,512)              norms
//   [512,1024)           masks (u32)
//   [1024, 1024+512*512) Dm
//   then accum: [0]=sum(f32) [1]=cnt(u32) [2]=done(u32)

// ---------------- prep: row norms + label bitmasks + zero accumulators -------
__global__ void prep_kernel(const float* __restrict__ src, const int* __restrict__ labels,
                            float* __restrict__ norms, unsigned* __restrict__ masks,
                            float* __restrict__ accum) {
    int i = blockIdx.x;        // one row per block, block = 64 (one wave)
    int lane = threadIdx.x;
    const float4* row = (const float4*)(src + (size_t)i * DD);
    float4 v0 = row[lane];
    float4 v1 = row[lane + 64];
    float s = v0.x*v0.x + v0.y*v0.y + v0.z*v0.z + v0.w*v0.w
            + v1.x*v1.x + v1.y*v1.y + v1.z*v1.z + v1.w*v1.w;
#pragma unroll
    for (int off = 32; off > 0; off >>= 1) s += __shfl_down(s, off);
    int lab = (lane < LL) ? labels[i * LL + lane] : 0;
    unsigned long long b = __ballot(lab != 0);
    if (lane == 0) {
        norms[i] = s;
        masks[i] = (unsigned)(b & 0xFFFFFFull);
        if (i == 0) {
            accum[0] = 0.0f;
            ((unsigned*)accum)[1] = 0u;   // count
            ((unsigned*)accum)[2] = 0u;   // done counter
        }
    }
}

// ---------------- dist: D[i][j] = ||s_i - s_j||  via Gram matrix -------------
__device__ __forceinline__ float dist_val(float d2, bool diag) {
    d2 = fmaxf(d2, 0.0f);
    float d = sqrtf(d2);
    return diag ? 0.0f : d;
}

__global__ void dist_kernel(const float* __restrict__ S, const float* __restrict__ norms,
                            float* __restrict__ Dm) {
    // 32x32 output tile per block, 256 threads (16x16), 2x2 micro-tile.
    // LDS tiles stored transposed: As[k][row] so micro reads are float2.
    __shared__ float As[32][34];
    __shared__ float Bs[32][34];
    int t  = threadIdx.x;
    int tx = t & 15, ty = t >> 4;
    int jb = blockIdx.x * 32;
    int ib = blockIdx.y * 32;
    int lr = t >> 3;            // 0..31  (tile row)
    int lc = (t & 7) * 4;       // 0,4,...,28 (k offset)
    float acc00 = 0.f, acc01 = 0.f, acc10 = 0.f, acc11 = 0.f;
    for (int k0 = 0; k0 < DD; k0 += 32) {
        float4 a = *(const float4*)&S[(size_t)(ib + lr) * DD + k0 + lc];
        float4 b = *(const float4*)&S[(size_t)(jb + lr) * DD + k0 + lc];
        As[lc + 0][lr] = a.x; As[lc + 1][lr] = a.y; As[lc + 2][lr] = a.z; As[lc + 3][lr] = a.w;
        Bs[lc + 0][lr] = b.x; Bs[lc + 1][lr] = b.y; Bs[lc + 2][lr] = b.z; Bs[lc + 3][lr] = b.w;
        __syncthreads();
#pragma unroll
        for (int kk = 0; kk < 32; kk++) {
            float2 av = *(const float2*)&As[kk][ty * 2];
            float2 bv = *(const float2*)&Bs[kk][tx * 2];
            acc00 += av.x * bv.x; acc01 += av.x * bv.y;
            acc10 += av.y * bv.x; acc11 += av.y * bv.y;
        }
        __syncthreads();
    }
    int i0 = ib + ty * 2, j0 = jb + tx * 2;
    float ni0 = norms[i0], ni1 = norms[i0 + 1];
    float nj0 = norms[j0], nj1 = norms[j0 + 1];
    float2 r0, r1;
    r0.x = dist_val(ni0 + nj0 - 2.f * acc00, i0     == j0    );
    r0.y = dist_val(ni0 + nj1 - 2.f * acc01, i0     == j0 + 1);
    r1.x = dist_val(ni1 + nj0 - 2.f * acc10, i0 + 1 == j0    );
    r1.y = dist_val(ni1 + nj1 - 2.f * acc11, i0 + 1 == j0 + 1);
    *(float2*)&Dm[(size_t)i0 * BN + j0]     = r0;
    *(float2*)&Dm[(size_t)(i0+1) * BN + j0] = r1;
}

// ---------------- triplet: compaction + pair sum + last-block finalize -------
__global__ void triplet_final_kernel(const float* __restrict__ Dm,
                                     const unsigned* __restrict__ masks,
                                     float* __restrict__ accum, float* __restrict__ out) {
    __shared__ float drow[BN];
    __shared__ float pos[BN];
    __shared__ float neg[BN];
    __shared__ int pcnt, ncnt;
    __shared__ float wsum[4];
    __shared__ unsigned wcnt[4];
    int i = blockIdx.x;
    int t = threadIdx.x;   // 256
    if (t == 0) { pcnt = 0; ncnt = 0; }
    float2 dv = ((const float2*)(Dm + (size_t)i * BN))[t];
    drow[2 * t] = dv.x; drow[2 * t + 1] = dv.y;
    __syncthreads();
    unsigned mi = masks[i];
#pragma unroll
    for (int j = t; j < BN; j += 256) {
        float dj = drow[j];
        if (mi & masks[j]) { int p = atomicAdd(&pcnt, 1); pos[p] = dj; }
        else               { int p = atomicAdd(&ncnt, 1); neg[p] = dj; }
    }
    __syncthreads();
    int P = pcnt, N = ncnt;
    float sum = 0.f;
    unsigned cnt = 0;
    for (int p = t; p < P; p += 256) {
        float a = pos[p];
        for (int n = 0; n < N; n++) {
            float v = a - neg[n];
            sum += fmaxf(v, 0.0f);
            cnt += (v > 1e-16f) ? 1u : 0u;
        }
    }
#pragma unroll
    for (int off = 32; off > 0; off >>= 1) {
        sum += __shfl_down(sum, off);
        cnt += __shfl_down(cnt, off);
    }
    if ((t & 63) == 0) { wsum[t >> 6] = sum; wcnt[t >> 6] = cnt; }
    __syncthreads();
    if (t == 0) {
        sum = wsum[0] + wsum[1] + wsum[2] + wsum[3];
        cnt = wcnt[0] + wcnt[1] + wcnt[2] + wcnt[3];
        atomicAdd(&accum[0], sum);
        atomicAdd(&((unsigned*)accum)[1], cnt);
        __threadfence();
        unsigned old = atomicAdd(&((unsigned*)accum)[2], 1u);
        if (old == (unsigned)(gridDim.x - 1)) {   // last block finalizes
            float s    = atomicAdd(&accum[0], 0.0f);
            unsigned c = atomicAdd(&((unsigned*)accum)[1], 0u);
            out[0] = s / ((float)c + 1e-16f);
        }
    }
}

extern "C" void kernel_launch(void* const* d_in, const int* in_sizes, int n_in,
                              void* d_out, int out_size, void* d_ws, size_t ws_size,
                              hipStream_t stream) {
    const float* src    = (const float*)d_in[0];
    const int*   labels = (const int*)d_in[1];
    float* ws = (float*)d_ws;
    float*    norms = ws;
    unsigned* masks = (unsigned*)(ws + BN);
    float*    Dm    = ws + 2 * BN;
    float*    accum = ws + 2 * BN + (size_t)BN * BN;

    hipLaunchKernelGGL(prep_kernel,          dim3(BN),     dim3(64),  0, stream,
                       src, labels, norms, masks, accum);
    hipLaunchKernelGGL(dist_kernel,          dim3(16, 16), dim3(256), 0, stream,
                       src, norms, Dm);
    hipLaunchKernelGGL(triplet_final_kernel, dim3(BN),     dim3(256), 0, stream,
                       Dm, masks, accum, (float*)d_out);
}

// Round 4
// 78.708 us; speedup vs baseline: 1.1991x; 1.1991x over previous
//
#include <hip/hip_runtime.h>

#define BN 512   // batch
#define DD 512   // feature dim
#define LL 24    // label dim

// ws layout (float words):
//   [0,512)              norms
//   [512,1024)           masks (u32)
//   [1024, 1024+512*512) Dm
//   then accum: [0]=sum(f32) [1]=cnt(u32)

// ---------------- prep: row norms + label bitmasks + zero accumulators -------
__global__ void prep_kernel(const float* __restrict__ src, const int* __restrict__ labels,
                            float* __restrict__ norms, unsigned* __restrict__ masks,
                            float* __restrict__ accum) {
    int i = blockIdx.x;        // one row per block, block = 64 (one wave)
    int lane = threadIdx.x;
    const float4* row = (const float4*)(src + (size_t)i * DD);
    float4 v0 = row[lane];
    float4 v1 = row[lane + 64];
    float s = v0.x*v0.x + v0.y*v0.y + v0.z*v0.z + v0.w*v0.w
            + v1.x*v1.x + v1.y*v1.y + v1.z*v1.z + v1.w*v1.w;
#pragma unroll
    for (int off = 32; off > 0; off >>= 1) s += __shfl_down(s, off);
    int lab = (lane < LL) ? labels[i * LL + lane] : 0;
    unsigned long long b = __ballot(lab != 0);
    if (lane == 0) {
        norms[i] = s;
        masks[i] = (unsigned)(b & 0xFFFFFFull);
        if (i == 0) { accum[0] = 0.0f; ((unsigned*)accum)[1] = 0u; }
    }
}

// ---------------- dist: D[i][j] = ||s_i - s_j||  via Gram matrix -------------
__device__ __forceinline__ float dist_val(float d2, bool diag) {
    d2 = fmaxf(d2, 0.0f);
    float d = sqrtf(d2);
    return diag ? 0.0f : d;
}

__global__ void dist_kernel(const float* __restrict__ S, const float* __restrict__ norms,
                            float* __restrict__ Dm) {
    // 32x32 output tile per block, 256 threads (16x16), 2x2 micro-tile.
    // LDS tiles stored transposed: As[k][row] so micro reads are float2.
    __shared__ float As[32][34];
    __shared__ float Bs[32][34];
    int t  = threadIdx.x;
    int tx = t & 15, ty = t >> 4;
    int jb = blockIdx.x * 32;
    int ib = blockIdx.y * 32;
    int lr = t >> 3;            // 0..31  (tile row)
    int lc = (t & 7) * 4;       // 0,4,...,28 (k offset)
    float acc00 = 0.f, acc01 = 0.f, acc10 = 0.f, acc11 = 0.f;
    for (int k0 = 0; k0 < DD; k0 += 32) {
        float4 a = *(const float4*)&S[(size_t)(ib + lr) * DD + k0 + lc];
        float4 b = *(const float4*)&S[(size_t)(jb + lr) * DD + k0 + lc];
        As[lc + 0][lr] = a.x; As[lc + 1][lr] = a.y; As[lc + 2][lr] = a.z; As[lc + 3][lr] = a.w;
        Bs[lc + 0][lr] = b.x; Bs[lc + 1][lr] = b.y; Bs[lc + 2][lr] = b.z; Bs[lc + 3][lr] = b.w;
        __syncthreads();
#pragma unroll
        for (int kk = 0; kk < 32; kk++) {
            float2 av = *(const float2*)&As[kk][ty * 2];
            float2 bv = *(const float2*)&Bs[kk][tx * 2];
            acc00 += av.x * bv.x; acc01 += av.x * bv.y;
            acc10 += av.y * bv.x; acc11 += av.y * bv.y;
        }
        __syncthreads();
    }
    int i0 = ib + ty * 2, j0 = jb + tx * 2;
    float ni0 = norms[i0], ni1 = norms[i0 + 1];
    float nj0 = norms[j0], nj1 = norms[j0 + 1];
    float2 r0, r1;
    r0.x = dist_val(ni0 + nj0 - 2.f * acc00, i0     == j0    );
    r0.y = dist_val(ni0 + nj1 - 2.f * acc01, i0     == j0 + 1);
    r1.x = dist_val(ni1 + nj0 - 2.f * acc10, i0 + 1 == j0    );
    r1.y = dist_val(ni1 + nj1 - 2.f * acc11, i0 + 1 == j0 + 1);
    *(float2*)&Dm[(size_t)i0 * BN + j0]     = r0;
    *(float2*)&Dm[(size_t)(i0+1) * BN + j0] = r1;
}

// ---------------- triplet: ballot compaction + pair sum ----------------------
__global__ void triplet_kernel(const float* __restrict__ Dm, const unsigned* __restrict__ masks,
                               float* __restrict__ accum) {
    __shared__ float pos[BN];
    __shared__ float neg[BN];
    __shared__ int pcnt, ncnt;
    __shared__ float wsum[4];
    __shared__ unsigned wcnt[4];
    const int i = blockIdx.x;
    const int t = threadIdx.x;          // 256
    const int lane = t & 63;
    const int w = t >> 6;
    if (t == 0) { pcnt = 0; ncnt = 0; }
    __syncthreads();
    const unsigned mi = masks[i];
    const float* drow = Dm + (size_t)i * BN;
    const unsigned long long ltmask = (1ull << lane) - 1ull;

    for (int j = t; j < BN; j += 256) {           // all 64 lanes active
        float dj = drow[j];
        bool isp = (mi & masks[j]) != 0u;
        unsigned long long bal = __ballot(isp);
        int np = __popcll(bal);
        if (np > 0) {
            int ldr = __ffsll((unsigned long long)bal) - 1;
            int base = 0;
            if (lane == ldr) base = atomicAdd(&pcnt, np);
            base = __shfl(base, ldr);
            if (isp) pos[base + __popcll(bal & ltmask)] = dj;
        }
        unsigned long long nbal = ~bal;
        int nn = 64 - np;
        if (nn > 0) {
            int ldr = __ffsll((unsigned long long)nbal) - 1;
            int base = 0;
            if (lane == ldr) base = atomicAdd(&ncnt, nn);
            base = __shfl(base, ldr);
            if (!isp) neg[base + __popcll(nbal & ltmask)] = dj;
        }
    }
    __syncthreads();

    const int P = pcnt, N = ncnt;
    float sum = 0.f;
    unsigned cnt = 0;
    for (int p = t; p < P; p += 256) {
        float a = pos[p];
        for (int n = 0; n < N; n++) {
            float v = a - neg[n];
            sum += fmaxf(v, 0.0f);
            cnt += (v > 1e-16f) ? 1u : 0u;
        }
    }
#pragma unroll
    for (int off = 32; off > 0; off >>= 1) {
        sum += __shfl_down(sum, off);
        cnt += __shfl_down(cnt, off);
    }
    if (lane == 0) { wsum[w] = sum; wcnt[w] = cnt; }
    __syncthreads();
    if (t == 0) {
        sum = wsum[0] + wsum[1] + wsum[2] + wsum[3];
        cnt = wcnt[0] + wcnt[1] + wcnt[2] + wcnt[3];
        if (sum != 0.f || cnt != 0u) {
            atomicAdd(&accum[0], sum);
            atomicAdd(&((unsigned*)accum)[1], cnt);
        }
    }
}

// ---------------- finalize ---------------------------------------------------
__global__ void finalize_kernel(const float* __restrict__ accum, float* __restrict__ out) {
    if (threadIdx.x == 0) {
        float s = accum[0];
        float c = (float)((const unsigned*)accum)[1];
        out[0] = s / (c + 1e-16f);
    }
}

extern "C" void kernel_launch(void* const* d_in, const int* in_sizes, int n_in,
                              void* d_out, int out_size, void* d_ws, size_t ws_size,
                              hipStream_t stream) {
    const float* src    = (const float*)d_in[0];
    const int*   labels = (const int*)d_in[1];
    float* ws = (float*)d_ws;
    float*    norms = ws;
    unsigned* masks = (unsigned*)(ws + BN);
    float*    Dm    = ws + 2 * BN;
    float*    accum = ws + 2 * BN + (size_t)BN * BN;

    hipLaunchKernelGGL(prep_kernel,     dim3(BN),     dim3(64),  0, stream, src, labels, norms, masks, accum);
    hipLaunchKernelGGL(dist_kernel,     dim3(16, 16), dim3(256), 0, stream, src, norms, Dm);
    hipLaunchKernelGGL(triplet_kernel,  dim3(BN),     dim3(256), 0, stream, Dm, masks, accum);
    hipLaunchKernelGGL(finalize_kernel, dim3(1),      dim3(64),  0, stream, accum, (float*)d_out);
}

// Round 5
// 75.097 us; speedup vs baseline: 1.2568x; 1.0481x over previous
//
#include <hip/hip_runtime.h>

#define BN 512   // batch
#define DD 512   // feature dim
#define LL 24    // label dim

typedef unsigned short u16;
typedef __attribute__((ext_vector_type(8))) short short8;  // 8 bf16 = 4 VGPR
typedef __attribute__((ext_vector_type(4))) float f32x4;

// ws layout (float words):
//   [0,512)                norms (f32)
//   [512,1024)             masks (u32)
//   [1024, 1024+262144)    Dm (f32, 512x512)
//   [263168, +131072)      S_hi (bf16 as u16, 512x512)
//   [394240, +131072)      S_lo (bf16 as u16, 512x512)
//   [525312]               accum: [0]=sum(f32) [1]=cnt(u32)

__device__ __forceinline__ u16 bf16_rn(float f) {
    unsigned u = __float_as_uint(f);
    return (u16)((u + 0x7FFFu + ((u >> 16) & 1u)) >> 16);
}
__device__ __forceinline__ float bf16_f(u16 h) {
    return __uint_as_float(((unsigned)h) << 16);
}

// ---------------- prep: norms + masks + bf16 hi/lo split + accum zero --------
__global__ void prep_kernel(const float* __restrict__ src, const int* __restrict__ labels,
                            float* __restrict__ norms, unsigned* __restrict__ masks,
                            u16* __restrict__ Sh, u16* __restrict__ Sl,
                            float* __restrict__ accum) {
    int i = blockIdx.x;        // one row per block, block = 64 (one wave)
    int lane = threadIdx.x;
    const float4* row = (const float4*)(src + (size_t)i * DD);
    float4 v0 = row[lane];           // k = 4*lane
    float4 v1 = row[lane + 64];      // k = 4*lane + 256
    float s = v0.x*v0.x + v0.y*v0.y + v0.z*v0.z + v0.w*v0.w
            + v1.x*v1.x + v1.y*v1.y + v1.z*v1.z + v1.w*v1.w;

    // bf16 hi/lo split, 8 elems per lane
    float f[8] = {v0.x, v0.y, v0.z, v0.w, v1.x, v1.y, v1.z, v1.w};
    u16 hi[8], lo[8];
#pragma unroll
    for (int e = 0; e < 8; e++) {
        hi[e] = bf16_rn(f[e]);
        lo[e] = bf16_rn(f[e] - bf16_f(hi[e]));
    }
    size_t o0 = (size_t)i * DD + 4 * lane;
    size_t o1 = o0 + 256;
    uint2 h0 = make_uint2((unsigned)hi[0] | ((unsigned)hi[1] << 16),
                          (unsigned)hi[2] | ((unsigned)hi[3] << 16));
    uint2 h1 = make_uint2((unsigned)hi[4] | ((unsigned)hi[5] << 16),
                          (unsigned)hi[6] | ((unsigned)hi[7] << 16));
    uint2 l0 = make_uint2((unsigned)lo[0] | ((unsigned)lo[1] << 16),
                          (unsigned)lo[2] | ((unsigned)lo[3] << 16));
    uint2 l1 = make_uint2((unsigned)lo[4] | ((unsigned)lo[5] << 16),
                          (unsigned)lo[6] | ((unsigned)lo[7] << 16));
    *(uint2*)(Sh + o0) = h0;  *(uint2*)(Sh + o1) = h1;
    *(uint2*)(Sl + o0) = l0;  *(uint2*)(Sl + o1) = l1;

#pragma unroll
    for (int off = 32; off > 0; off >>= 1) s += __shfl_down(s, off);
    int lab = (lane < LL) ? labels[i * LL + lane] : 0;
    unsigned long long b = __ballot(lab != 0);
    if (lane == 0) {
        norms[i] = s;
        masks[i] = (unsigned)(b & 0xFFFFFFull);
        if (i == 0) { accum[0] = 0.0f; ((unsigned*)accum)[1] = 0u; }
    }
}

// ---------------- dist via bf16-split MFMA Gram, no LDS ----------------------
__device__ __forceinline__ float dist_val(float d2, bool diag) {
    d2 = fmaxf(d2, 0.0f);
    float d = sqrtf(d2);
    return diag ? 0.0f : d;
}

__global__ __launch_bounds__(64) void dist_mfma_kernel(
    const u16* __restrict__ Sh, const u16* __restrict__ Sl,
    const float* __restrict__ norms, float* __restrict__ Dm)
{
    const int l    = threadIdx.x;
    const int r    = l & 15;        // fragment row index (A.m / B.n / C.col)
    const int half = l >> 4;        // 0..3 -> k-base half*8, C.row base half*4
    const int jb = blockIdx.x * 32;
    const int ib = blockIdx.y * 32;
    const int kb = half * 8;

    // row-major bases; fragment = 8 contiguous bf16 at (row, k0+kb)
    const u16* pA0h = Sh + (size_t)(ib + r)      * DD + kb;
    const u16* pA1h = Sh + (size_t)(ib + 16 + r) * DD + kb;
    const u16* pB0h = Sh + (size_t)(jb + r)      * DD + kb;
    const u16* pB1h = Sh + (size_t)(jb + 16 + r) * DD + kb;
    const u16* pA0l = Sl + (size_t)(ib + r)      * DD + kb;
    const u16* pA1l = Sl + (size_t)(ib + 16 + r) * DD + kb;
    const u16* pB0l = Sl + (size_t)(jb + r)      * DD + kb;
    const u16* pB1l = Sl + (size_t)(jb + 16 + r) * DD + kb;

    f32x4 acc00 = {0.f,0.f,0.f,0.f}, acc01 = acc00, acc10 = acc00, acc11 = acc00;

    short8 a0h = *(const short8*)(pA0h), a1h = *(const short8*)(pA1h);
    short8 b0h = *(const short8*)(pB0h), b1h = *(const short8*)(pB1h);
    short8 a0l = *(const short8*)(pA0l), a1l = *(const short8*)(pA1l);
    short8 b0l = *(const short8*)(pB0l), b1l = *(const short8*)(pB1l);

    for (int k0 = 0; k0 < DD; k0 += 32) {
        short8 na0h, na1h, nb0h, nb1h, na0l, na1l, nb0l, nb1l;
        const int kn = k0 + 32;
        if (kn < DD) {              // uniform branch: prefetch next k-step
            na0h = *(const short8*)(pA0h + kn); na1h = *(const short8*)(pA1h + kn);
            nb0h = *(const short8*)(pB0h + kn); nb1h = *(const short8*)(pB1h + kn);
            na0l = *(const short8*)(pA0l + kn); na1l = *(const short8*)(pA1l + kn);
            nb0l = *(const short8*)(pB0l + kn); nb1l = *(const short8*)(pB1l + kn);
        }
        // g = hi*hi + hi*lo + lo*hi   (lo*lo dropped, ~2^-32)
        acc00 = __builtin_amdgcn_mfma_f32_16x16x32_bf16(a0h, b0h, acc00, 0, 0, 0);
        acc01 = __builtin_amdgcn_mfma_f32_16x16x32_bf16(a0h, b1h, acc01, 0, 0, 0);
        acc10 = __builtin_amdgcn_mfma_f32_16x16x32_bf16(a1h, b0h, acc10, 0, 0, 0);
        acc11 = __builtin_amdgcn_mfma_f32_16x16x32_bf16(a1h, b1h, acc11, 0, 0, 0);
        acc00 = __builtin_amdgcn_mfma_f32_16x16x32_bf16(a0h, b0l, acc00, 0, 0, 0);
        acc01 = __builtin_amdgcn_mfma_f32_16x16x32_bf16(a0h, b1l, acc01, 0, 0, 0);
        acc10 = __builtin_amdgcn_mfma_f32_16x16x32_bf16(a1h, b0l, acc10, 0, 0, 0);
        acc11 = __builtin_amdgcn_mfma_f32_16x16x32_bf16(a1h, b1l, acc11, 0, 0, 0);
        acc00 = __builtin_amdgcn_mfma_f32_16x16x32_bf16(a0l, b0h, acc00, 0, 0, 0);
        acc01 = __builtin_amdgcn_mfma_f32_16x16x32_bf16(a0l, b1h, acc01, 0, 0, 0);
        acc10 = __builtin_amdgcn_mfma_f32_16x16x32_bf16(a1l, b0h, acc10, 0, 0, 0);
        acc11 = __builtin_amdgcn_mfma_f32_16x16x32_bf16(a1l, b1h, acc11, 0, 0, 0);
        a0h = na0h; a1h = na1h; b0h = nb0h; b1h = nb1h;
        a0l = na0l; a1l = na1l; b0l = nb0l; b1l = nb1l;
    }

    // C/D layout (verified m89/m91): col = lane&15, row = (lane>>4)*4 + reg
    const int jc0 = jb + r, jc1 = jb + 16 + r;
    const float nj0 = norms[jc0], nj1 = norms[jc1];
#pragma unroll
    for (int p = 0; p < 4; p++) {
        const int ir0 = ib + half * 4 + p;
        const int ir1 = ir0 + 16;
        const float ni0 = norms[ir0], ni1 = norms[ir1];
        Dm[(size_t)ir0 * BN + jc0] = dist_val(ni0 + nj0 - 2.f * acc00[p], ir0 == jc0);
        Dm[(size_t)ir0 * BN + jc1] = dist_val(ni0 + nj1 - 2.f * acc01[p], ir0 == jc1);
        Dm[(size_t)ir1 * BN + jc0] = dist_val(ni1 + nj0 - 2.f * acc10[p], ir1 == jc0);
        Dm[(size_t)ir1 * BN + jc1] = dist_val(ni1 + nj1 - 2.f * acc11[p], ir1 == jc1);
    }
}

// ---------------- triplet: ballot compaction + pair sum (R4, measured) -------
__global__ void triplet_kernel(const float* __restrict__ Dm, const unsigned* __restrict__ masks,
                               float* __restrict__ accum) {
    __shared__ float pos[BN];
    __shared__ float neg[BN];
    __shared__ int pcnt, ncnt;
    __shared__ float wsum[4];
    __shared__ unsigned wcnt[4];
    const int i = blockIdx.x;
    const int t = threadIdx.x;          // 256
    const int lane = t & 63;
    const int w = t >> 6;
    if (t == 0) { pcnt = 0; ncnt = 0; }
    __syncthreads();
    const unsigned mi = masks[i];
    const float* drow = Dm + (size_t)i * BN;
    const unsigned long long ltmask = (1ull << lane) - 1ull;

    for (int j = t; j < BN; j += 256) {
        float dj = drow[j];
        bool isp = (mi & masks[j]) != 0u;
        unsigned long long bal = __ballot(isp);
        int np = __popcll(bal);
        if (np > 0) {
            int ldr = __ffsll((unsigned long long)bal) - 1;
            int base = 0;
            if (lane == ldr) base = atomicAdd(&pcnt, np);
            base = __shfl(base, ldr);
            if (isp) pos[base + __popcll(bal & ltmask)] = dj;
        }
        unsigned long long nbal = ~bal;
        int nn = 64 - np;
        if (nn > 0) {
            int ldr = __ffsll((unsigned long long)nbal) - 1;
            int base = 0;
            if (lane == ldr) base = atomicAdd(&ncnt, nn);
            base = __shfl(base, ldr);
            if (!isp) neg[base + __popcll(nbal & ltmask)] = dj;
        }
    }
    __syncthreads();

    const int P = pcnt, N = ncnt;
    float sum = 0.f;
    unsigned cnt = 0;
    for (int p = t; p < P; p += 256) {
        float a = pos[p];
        for (int n = 0; n < N; n++) {
            float v = a - neg[n];
            sum += fmaxf(v, 0.0f);
            cnt += (v > 1e-16f) ? 1u : 0u;
        }
    }
#pragma unroll
    for (int off = 32; off > 0; off >>= 1) {
        sum += __shfl_down(sum, off);
        cnt += __shfl_down(cnt, off);
    }
    if (lane == 0) { wsum[w] = sum; wcnt[w] = cnt; }
    __syncthreads();
    if (t == 0) {
        sum = wsum[0] + wsum[1] + wsum[2] + wsum[3];
        cnt = wcnt[0] + wcnt[1] + wcnt[2] + wcnt[3];
        if (sum != 0.f || cnt != 0u) {
            atomicAdd(&accum[0], sum);
            atomicAdd(&((unsigned*)accum)[1], cnt);
        }
    }
}

// ---------------- finalize ---------------------------------------------------
__global__ void finalize_kernel(const float* __restrict__ accum, float* __restrict__ out) {
    if (threadIdx.x == 0) {
        float s = accum[0];
        float c = (float)((const unsigned*)accum)[1];
        out[0] = s / (c + 1e-16f);
    }
}

extern "C" void kernel_launch(void* const* d_in, const int* in_sizes, int n_in,
                              void* d_out, int out_size, void* d_ws, size_t ws_size,
                              hipStream_t stream) {
    const float* src    = (const float*)d_in[0];
    const int*   labels = (const int*)d_in[1];
    float* ws = (float*)d_ws;
    float*    norms = ws;
    unsigned* masks = (unsigned*)(ws + BN);
    float*    Dm    = ws + 2 * BN;
    u16*      Sh    = (u16*)(ws + 2 * BN + (size_t)BN * BN);
    u16*      Sl    = Sh + (size_t)BN * DD;
    float*    accum = ws + 2 * BN + (size_t)BN * BN + BN * DD;  // after Sh+Sl (2*BN*DD u16 = BN*DD floats)

    hipLaunchKernelGGL(prep_kernel,      dim3(BN),     dim3(64),  0, stream,
                       src, labels, norms, masks, Sh, Sl, accum);
    hipLaunchKernelGGL(dist_mfma_kernel, dim3(16, 16), dim3(64),  0, stream,
                       Sh, Sl, norms, Dm);
    hipLaunchKernelGGL(triplet_kernel,   dim3(BN),     dim3(256), 0, stream,
                       Dm, masks, accum);
    hipLaunchKernelGGL(finalize_kernel,  dim3(1),      dim3(64),  0, stream,
                       accum, (float*)d_out);
}